// Round 15
// baseline (228.072 us; speedup 1.0000x reference)
//
#include <hip/hip_runtime.h>

// Partial-CRF NLL: chunked scan with DUAL-CHAIN ILP consumer.
// 256 blocks x 320 threads = 1 block/CU; block = (grp = bid&63, pair = bid>>6).
// Consumer wave runs TWO chunk-recurrences interleaved: X = chunk pair,
// Y = chunk pair+4 (8 chunks x 64 steps). A-frags (112 VGPR) shared by both.
// Uniform NSTEPS = 80 (W=16 warmup; pair0-X: 17 frozen dummy steps + exact
// t=0 init). Rescale at t == 3 (mod 4); warmup anchor t = 64ck-1 is a rescale;
// logZ reset after warmup (group j==3); owner chunk (last active step inside
// its 64-step window) adds the STOP term. Stitching invariant = R13/R14
// (absmax 0.0). Per-step machinery = R12: sigma-permuted register P, 28 bf16
// MFMA (2x 2-deep chains), tile-6 ds_bpermute.
// Ring: 8 slabs per chain (16 total, 72KB); group-4 coupling (flag = k+4,
// producer waits cfv >= kk-4); 4 producer waves x 2 batches x 2 chains.

typedef short s16x4 __attribute__((ext_vector_type(4)));
typedef short bf16x8 __attribute__((ext_vector_type(8)));
typedef float f32x4 __attribute__((ext_vector_type(4)));

constexpr int T = 512, L = 102;
constexpr int MS = 132;        // slab row stride (shorts)
constexpr int SLAB = 16 * MS;  // shorts per slab
constexpr int W = 16;          // warmup steps
constexpr int NSTEPS = 80;     // 16 warmup/dummy + 64 owned

__device__ __forceinline__ float bf2f(short s) {
  return __uint_as_float(((unsigned)(unsigned short)s) << 16);
}
__device__ __forceinline__ short f2bf(float x) {  // RNE, cold paths
  unsigned u = __float_as_uint(x);
  u += 0x7fffu + ((u >> 16) & 1u);
  return (short)(u >> 16);
}
__device__ __forceinline__ bf16x8 mk8(unsigned a, unsigned b, unsigned c,
                                      unsigned d) {
  union { unsigned u[4]; bf16x8 v; } x;
  x.u[0] = a; x.u[1] = b; x.u[2] = c; x.u[3] = d;
  return x.v;
}

struct Raw { s16x4 m[7]; };

#define STEP(SBn, MMVv, RESv, RU, RL, PKA, PKB, LOGZ)                        \
  {                                                                          \
    const bool mmv = (MMVv) != 0;                                            \
    const unsigned q3d0 =                                                    \
        ((unsigned)__builtin_amdgcn_ds_bpermute(bpa, (int)PKA[6])) & himask; \
    const unsigned q3d1 =                                                    \
        ((unsigned)__builtin_amdgcn_ds_bpermute(bpa, (int)PKB[6])) & himask; \
    const unsigned q3d2 =                                                    \
        ((unsigned)__builtin_amdgcn_ds_bpermute(bpb, (int)PKA[6])) & himask; \
    const unsigned q3d3 =                                                    \
        ((unsigned)__builtin_amdgcn_ds_bpermute(bpb, (int)PKB[6])) & himask; \
    float fu[28];                                                            \
    _Pragma("unroll") for (int Tt = 0; Tt < 7; ++Tt) {                       \
      fu[4 * Tt + 0] = bf2f(RU.m[Tt][0]);                                    \
      fu[4 * Tt + 1] = bf2f(RU.m[Tt][1]);                                    \
      fu[4 * Tt + 2] = bf2f(RU.m[Tt][2]);                                    \
      fu[4 * Tt + 3] = bf2f(RU.m[Tt][3]);                                    \
    }                                                                        \
    const short* sln = mlb + (SBn) + cc * MS;                                \
    RL.m[0] = *(const s16x4*)(sln + 0 + 8 * hi);                             \
    RL.m[1] = *(const s16x4*)(sln + 4 + 8 * hi);                             \
    RL.m[2] = *(const s16x4*)(sln + 32 + 8 * hi);                            \
    RL.m[3] = *(const s16x4*)(sln + 36 + 8 * hi);                            \
    RL.m[4] = *(const s16x4*)(sln + 64 + 8 * hi);                            \
    RL.m[5] = *(const s16x4*)(sln + 68 + 8 * hi);                            \
    RL.m[6] = *(const s16x4*)(sln + 96 + 4 * hi);                            \
    const bf16x8 q0 = mk8(PKA[0], PKB[0], PKA[1], PKB[1]);                   \
    const bf16x8 q1 = mk8(PKA[2], PKB[2], PKA[3], PKB[3]);                   \
    const bf16x8 q2 = mk8(PKA[4], PKB[4], PKA[5], PKB[5]);                   \
    const bf16x8 q3 = mk8(q3d0, q3d1, q3d2, q3d3);                           \
    f32x4 a01[7], a23[7];                                                    \
    _Pragma("unroll") for (int Tt = 0; Tt < 7; ++Tt)                         \
      a01[Tt] = __builtin_amdgcn_mfma_f32_16x16x32_bf16(ef[Tt][0], q0, zf,   \
                                                        0, 0, 0);            \
    _Pragma("unroll") for (int Tt = 0; Tt < 7; ++Tt)                         \
      a23[Tt] = __builtin_amdgcn_mfma_f32_16x16x32_bf16(ef[Tt][2], q2, zf,   \
                                                        0, 0, 0);            \
    _Pragma("unroll") for (int Tt = 0; Tt < 7; ++Tt)                         \
      a01[Tt] = __builtin_amdgcn_mfma_f32_16x16x32_bf16(ef[Tt][1], q1,       \
                                                        a01[Tt], 0, 0, 0);   \
    _Pragma("unroll") for (int Tt = 0; Tt < 7; ++Tt)                         \
      a23[Tt] = __builtin_amdgcn_mfma_f32_16x16x32_bf16(ef[Tt][3], q3,       \
                                                        a23[Tt], 0, 0, 0);   \
    f32x4 dd[7];                                                             \
    _Pragma("unroll") for (int Tt = 0; Tt < 7; ++Tt)                         \
      dd[Tt] = a01[Tt] + a23[Tt];                                            \
    float cs = 1.f;                                                          \
    if (RESv) {                                                              \
      const float w1r = dd[0][1] * fu[1];                                    \
      const float spre = mmv ? w1r : 1.0f;                                   \
      const float sh = __shfl(spre, cc);                                     \
      cs = __builtin_amdgcn_rcpf(sh);                                        \
      LOGZ += __logf(sh);                                                    \
    }                                                                        \
    _Pragma("unroll") for (int Tt = 0; Tt < 7; ++Tt) {                       \
      float w0 = dd[Tt][0] * fu[4 * Tt + 0];                                 \
      float w1 = dd[Tt][1] * fu[4 * Tt + 1];                                 \
      float w2 = dd[Tt][2] * fu[4 * Tt + 2];                                 \
      float w3 = dd[Tt][3] * fu[4 * Tt + 3];                                 \
      if (RESv) { w0 *= cs; w1 *= cs; w2 *= cs; w3 *= cs; }                  \
      unsigned lo_, hi_;                                                     \
      asm("v_cvt_pk_bf16_f32 %0, %1, %2" : "=v"(lo_) : "v"(w0), "v"(w1));    \
      asm("v_cvt_pk_bf16_f32 %0, %1, %2" : "=v"(hi_) : "v"(w2), "v"(w3));    \
      PKA[Tt] = mmv ? lo_ : PKA[Tt];                                         \
      PKB[Tt] = mmv ? hi_ : PKB[Tt];                                         \
    }                                                                        \
  }

__global__ __launch_bounds__(320, 1)
void crf_scan(const float* __restrict__ emit,
              const float* __restrict__ trans,
              const unsigned char* __restrict__ mask_b,
              const unsigned char* __restrict__ um_b,
              float* __restrict__ partials)
{
  const int tid = threadIdx.x, wid = tid >> 6, lane = tid & 63;
  const int bid = blockIdx.x;
  const int grp = bid & 63, pair = bid >> 6;      // pair in 0..3
  const int b8 = grp * 8;
  const int t0X = pair << 6, t0Y = (pair + 4) << 6;
  const int tfX = t0X - W, tfY = t0Y - W;         // X at pair0: dummies t<1
  // bool layout: um[0,0,1] always True -> byte1==1 iff uint8, else LE int32
  const int ush = (um_b[1] != 0) ? 0 : 2;

  __shared__ __align__(16) short Ml[2][8][16][MS];
  __shared__ unsigned char Kmask[8][T];
  __shared__ int sflags[5];

  volatile int* pf0 = (volatile int*)&sflags[0];
  volatile int* pf1 = (volatile int*)&sflags[1];
  volatile int* pf2 = (volatile int*)&sflags[2];
  volatile int* pf3 = (volatile int*)&sflags[3];
  volatile int* cfv = (volatile int*)&sflags[4];

  if (wid != 0) {
    // ================= producer waves (wid 1..4, 2 batches each) =========
    const int p    = wid - 1;
    const int boff = 2 * p;
    const int tagp = 2 * lane;
    const int tagc = (tagp <= 100) ? tagp : 100;
    const bool tv  = (tagp <= 100);

    if (lane == 0) sflags[p] = 0;
    for (int i = lane; i < 2 * T; i += 64) {       // my 2 Kmask rows (full)
      const int bb_ = i >> 9, tt = i & 511;
      Kmask[boff + bb_][tt] =
          mask_b[(((size_t)(b8 + boff + bb_)) * T + tt) << ush];
    }

    struct SetG { float2 e[4][2][2]; uint2 u[4][2][2]; };  // [step][chain][b]
    SetG SA, SB;                                   // static names (rule #20)

    auto issueG = [&](int kk, SetG& S) {
#pragma unroll
      for (int s = 0; s < 4; ++s) {
#pragma unroll
        for (int c2 = 0; c2 < 2; ++c2) {
          int t = (c2 ? tfY : tfX) + kk + s;
          t = (t < 1) ? 1 : ((t > 511) ? 511 : t);
#pragma unroll
          for (int i = 0; i < 2; ++i) {
            const size_t base = ((size_t)(b8 + boff + i) * T + t) * (size_t)L;
            S.e[s][c2][i] = *(const float2*)(emit + base + tagc);
            if (ush == 0) {
              const unsigned us =
                  *(const unsigned short*)(um_b + base + tagc);
              S.u[s][c2][i].x = us & 255u; S.u[s][c2][i].y = us >> 8;
            } else {
              S.u[s][c2][i] = *(const uint2*)(um_b + ((base + tagc) << 2));
            }
          }
        }
      }
    };
    auto stageG = [&](int kk, SetG& S) {
#pragma unroll
      for (int s = 0; s < 4; ++s) {
#pragma unroll
        for (int c2 = 0; c2 < 2; ++c2) {
          short* slab = &Ml[c2][(kk + s) & 7][0][0];
#pragma unroll
          for (int i = 0; i < 2; ++i) {
            const float e0 = tv ? __expf(S.e[s][c2][i].x) : 0.f;
            const float e1_ = tv ? __expf(S.e[s][c2][i].y) : 0.f;
            const float g0 = S.u[s][c2][i].x ? e0 : 0.f;
            const float g1 = S.u[s][c2][i].y ? e1_ : 0.f;
            unsigned pe, pg;
            asm("v_cvt_pk_bf16_f32 %0, %1, %2" : "=v"(pe) : "v"(e0), "v"(e1_));
            asm("v_cvt_pk_bf16_f32 %0, %1, %2" : "=v"(pg) : "v"(g0), "v"(g1));
            *(unsigned*)(slab + (2 * (boff + i))     * MS + tagp) = pe;
            *(unsigned*)(slab + (2 * (boff + i) + 1) * MS + tagp) = pg;
          }
        }
      }
    };

    volatile int* myf = (p == 0) ? pf0 : (p == 1) ? pf1 : (p == 2) ? pf2 : pf3;
    __syncthreads();
    issueG(0, SA); issueG(4, SB);
    int csn = 0;

#define PB(kk, S)                                                  \
    {                                                              \
      if ((kk) >= 8 && csn < (kk) - 4) {                           \
        int v; do { v = *cfv; } while (v < (kk) - 4);              \
        csn = v;                                                   \
      }                                                            \
      stageG((kk), S);                                             \
      asm volatile("s_waitcnt lgkmcnt(0)" ::: "memory");           \
      if (lane == 0) *myf = (kk) + 4;                              \
      issueG((kk) + 8, S);                                         \
    }
    for (int kk = 0; kk < NSTEPS; kk += 8) {
      PB(kk, SA)
      PB(kk + 4, SB)
    }
#undef PB
  } else {
    // ========================= consumer wave =========================
    if (lane == 0) sflags[4] = 0;
    __builtin_amdgcn_s_setprio(1);
    const int cc = lane & 15, hi = lane >> 4;
    const int myb = cc >> 1, batch = b8 + myb, goldc = cc & 1;
    const bool pair0 = (pair == 0);

    // A-frags (R6-verified), SHARED by both chains
    bf16x8 ef[7][4];
#pragma unroll
    for (int Tt = 0; Tt < 7; ++Tt) {
      const int g = (Tt < 6)
          ? (32 * (Tt >> 1) + 4 * (Tt & 1) + 8 * (cc >> 2) + (cc & 3))
          : (96 + cc);
#pragma unroll
      for (int kk = 0; kk < 4; ++kk) {
        bf16x8 v;
#pragma unroll
        for (int j = 0; j < 8; ++j) {
          const int k = 32 * kk + 8 * hi + j;
          float e = 0.f;
          if (k < L && g < L) e = __expf(trans[k * L + g]);
          v[j] = f2bf(e);
        }
        ef[Tt][kk] = v;
      }
    }

    // init: X = exact (pair 0) or uniform; Y = uniform always
    unsigned pkXA[7], pkXB[7], pkYA[7], pkYB[7];
    const size_t e0b = (size_t)batch * T * L;
    const unsigned one2 = 0x3F803F80u;             // bf16 {1.0, 1.0}
#pragma unroll
    for (int Tt = 0; Tt < 6; ++Tt) { pkYA[Tt] = one2; pkYB[Tt] = one2; }
    pkYA[6] = (hi == 0) ? one2 : ((hi == 1) ? one2 : 0u);
    pkYB[6] = (hi == 0) ? one2 : 0u;
    if (pair0) {
#pragma unroll
      for (int Tt = 0; Tt < 7; ++Tt) {
        const int s0 = (Tt < 6) ? (32 * (Tt >> 1) + 4 * (Tt & 1) + 8 * hi)
                                : (96 + 4 * hi);
        float w[4];
#pragma unroll
        for (int r = 0; r < 4; ++r) {
          const int tg = s0 + r;
          float x = 0.f;
          if (tg < L) {
            x = __expf(emit[e0b + tg] + trans[100 * L + tg]);
            if (goldc && !um_b[((size_t)(e0b + tg)) << ush]) x = 0.f;
          }
          w[r] = x;
        }
        asm("v_cvt_pk_bf16_f32 %0, %1, %2" : "=v"(pkXA[Tt]) : "v"(w[0]), "v"(w[1]));
        asm("v_cvt_pk_bf16_f32 %0, %1, %2" : "=v"(pkXB[Tt]) : "v"(w[2]), "v"(w[3]));
      }
    } else {
#pragma unroll
      for (int Tt = 0; Tt < 6; ++Tt) { pkXA[Tt] = one2; pkXB[Tt] = one2; }
      pkXA[6] = (hi == 0) ? one2 : ((hi == 1) ? one2 : 0u);
      pkXB[6] = (hi == 0) ? one2 : 0u;
    }

    const int bpa = (cc + 16 * ((2 * hi) & 3)) << 2;       // tile-6 bpermute
    const int bpb = (cc + 16 * ((2 * hi + 1) & 3)) << 2;
    const unsigned himask = (hi < 2) ? 0xffffffffu : 0u;
    const short* mlb = &Ml[0][0][0][0];
    const unsigned* kmr = (const unsigned*)&Kmask[myb][0];
    const f32x4 zf = {0.f, 0.f, 0.f, 0.f};
    Raw rXA, rXB, rYA, rYB;
    float logZX = 0.f, logZY = 0.f;
    int seen = 0;

    __syncthreads();

    {   // initial poll (groups 0,1 staged) + preload rXA/rYA from slab 0
      int v0, v1, v2, v3;
      do { v0 = *pf0; v1 = *pf1; v2 = *pf2; v3 = *pf3; }
      while (v0 < 8 || v1 < 8 || v2 < 8 || v3 < 8);
      int mn = v0 < v1 ? v0 : v1; mn = mn < v2 ? mn : v2;
      seen = mn < v3 ? mn : v3;
      int sbX = 0, sbY = 8 * SLAB;
      asm volatile("" : "+v"(sbX), "+v"(sbY) : "v"(seen));
      const short* sx = mlb + sbX + cc * MS;
      rXA.m[0] = *(const s16x4*)(sx + 0 + 8 * hi);
      rXA.m[1] = *(const s16x4*)(sx + 4 + 8 * hi);
      rXA.m[2] = *(const s16x4*)(sx + 32 + 8 * hi);
      rXA.m[3] = *(const s16x4*)(sx + 36 + 8 * hi);
      rXA.m[4] = *(const s16x4*)(sx + 64 + 8 * hi);
      rXA.m[5] = *(const s16x4*)(sx + 68 + 8 * hi);
      rXA.m[6] = *(const s16x4*)(sx + 96 + 4 * hi);
      const short* sy = mlb + sbY + cc * MS;
      rYA.m[0] = *(const s16x4*)(sy + 0 + 8 * hi);
      rYA.m[1] = *(const s16x4*)(sy + 4 + 8 * hi);
      rYA.m[2] = *(const s16x4*)(sy + 32 + 8 * hi);
      rYA.m[3] = *(const s16x4*)(sy + 36 + 8 * hi);
      rYA.m[4] = *(const s16x4*)(sy + 64 + 8 * hi);
      rYA.m[5] = *(const s16x4*)(sy + 68 + 8 * hi);
      rYA.m[6] = *(const s16x4*)(sy + 96 + 4 * hi);
    }

    for (int j = 0; j < 20; ++j) {
      const int k0 = 4 * j;
      const int need = (k0 + 8 < NSTEPS) ? k0 + 8 : NSTEPS;
      if (seen < need) {
        int v0, v1, v2, v3;
        do { v0 = *pf0; v1 = *pf1; v2 = *pf2; v3 = *pf3; }
        while (v0 < need || v1 < need || v2 < need || v3 < need);
        int mn = v0 < v1 ? v0 : v1; mn = mn < v2 ? mn : v2;
        seen = mn < v3 ? mn : v3;
      }
      const int kc = NSTEPS - 1;
      int x1 = (((k0 + 1 < kc) ? k0 + 1 : kc) & 7) * SLAB;
      int x2 = (((k0 + 2 < kc) ? k0 + 2 : kc) & 7) * SLAB;
      int x3 = (((k0 + 3 < kc) ? k0 + 3 : kc) & 7) * SLAB;
      int x4 = (((k0 + 4 < kc) ? k0 + 4 : kc) & 7) * SLAB;
      int y1 = 8 * SLAB + x1, y2 = 8 * SLAB + x2;
      int y3 = 8 * SLAB + x3, y4 = 8 * SLAB + x4;
      asm volatile("" : "+v"(x1), "+v"(x2), "+v"(x3), "+v"(x4) : "v"(seen));
      // masks (tb % 4 == 0)
      unsigned wX;
      {
        const int tbX = tfX + k0;
        wX = (tbX >= 0) ? kmr[tbX >> 2] : 0u;
        if (pair0 && tbX == 0) wX &= ~255u;       // t = 0 is the init, not a step
      }
      const unsigned wY = kmr[(tfY + k0) >> 2];
      const unsigned mX0 = wX & 255u, mX1 = (wX >> 8) & 255u;
      const unsigned mX2 = (wX >> 16) & 255u, mX3 = wX >> 24;
      const unsigned mY0 = wY & 255u, mY1 = (wY >> 8) & 255u;
      const unsigned mY2 = (wY >> 16) & 255u, mY3 = wY >> 24;
      STEP(x1, mX0, false, rXA, rXB, pkXA, pkXB, logZX)
      STEP(y1, mY0, false, rYA, rYB, pkYA, pkYB, logZY)
      STEP(x2, mX1, false, rXB, rXA, pkXA, pkXB, logZX)
      STEP(y2, mY1, false, rYB, rYA, pkYA, pkYB, logZY)
      STEP(x3, mX2, false, rXA, rXB, pkXA, pkXB, logZX)
      STEP(y3, mY2, false, rYA, rYB, pkYA, pkYB, logZY)
      STEP(x4, mX3, true,  rXB, rXA, pkXA, pkXB, logZX)
      STEP(y4, mY3, true,  rYB, rYA, pkYA, pkYB, logZY)
      asm volatile("s_waitcnt lgkmcnt(0)" ::: "memory");
      if (lane == 0) *cfv = k0 + 4;
      if (j == 3) {                               // end-of-warmup anchors
        if (!pair0) logZX = 0.f;
        logZY = 0.f;
      }
    }

    // finals: tot over sigma map per chain; owner adds STOP term
    float totX = 0.f, totY = 0.f;
#pragma unroll
    for (int Tt = 0; Tt < 7; ++Tt) {
      const int s0 = (Tt < 6) ? (32 * (Tt >> 1) + 4 * (Tt & 1) + 8 * hi)
                              : (96 + 4 * hi);
#pragma unroll
      for (int r = 0; r < 4; ++r) {
        const int tg = s0 + r;
        if (tg < L) {
          const float es = __expf(trans[tg * L + 101]);
          const unsigned pvX = (r < 2) ? pkXA[Tt] : pkXB[Tt];
          const unsigned pvY = (r < 2) ? pkYA[Tt] : pkYB[Tt];
          const short bX = (short)((r & 1) ? (pvX >> 16) : (pvX & 0xffffu));
          const short bY = (short)((r & 1) ? (pvY >> 16) : (pvY & 0xffffu));
          totX += bf2f(bX) * es;
          totY += bf2f(bY) * es;
        }
      }
    }
    totX += __shfl_xor(totX, 16); totX += __shfl_xor(totX, 32);
    totY += __shfl_xor(totY, 16); totY += __shfl_xor(totY, 32);
    const int ownX = (int)Kmask[myb][t0X] & (1 - (int)Kmask[myb][t0X + 64]);
    const int actYe = (pair == 3) ? 0 : (int)Kmask[myb][t0Y + 64];
    const int ownY = (int)Kmask[myb][t0Y] & (1 - actYe);
    const float scoreX = logZX + (ownX ? __logf(totX) : 0.f);
    const float scoreY = logZY + (ownY ? __logf(totY) : 0.f);
    float sgn = goldc ? -(scoreX + scoreY) : (scoreX + scoreY);
    sgn += __shfl_xor(sgn, 1);
    sgn += __shfl_xor(sgn, 2);
    sgn += __shfl_xor(sgn, 4);
    sgn += __shfl_xor(sgn, 8);
    if (lane == 0) partials[bid] = sgn;
  }
}

__global__ void reduce_partials(const float* __restrict__ part,
                                float* __restrict__ out) {
  const int tid = threadIdx.x;
  float v = part[tid];
#pragma unroll
  for (int s = 1; s < 64; s <<= 1) v += __shfl_xor(v, s);
  __shared__ float ws[4];
  if ((tid & 63) == 0) ws[tid >> 6] = v;
  __syncthreads();
  if (tid == 0) out[0] = ws[0] + ws[1] + ws[2] + ws[3];
}

extern "C" void kernel_launch(void* const* d_in, const int* in_sizes, int n_in,
                              void* d_out, int out_size, void* d_ws,
                              size_t ws_size, hipStream_t stream) {
  const float* emit = (const float*)d_in[0];
  const float* trn  = (const float*)d_in[1];
  const unsigned char* msk = (const unsigned char*)d_in[2];
  const unsigned char* umk = (const unsigned char*)d_in[3];
  float* out = (float*)d_out;
  float* pw  = (float*)d_ws;   // 256 block partials

  crf_scan<<<dim3(256), dim3(320), 0, stream>>>(emit, trn, msk, umk, pw);
  reduce_partials<<<dim3(1), dim3(256), 0, stream>>>(pw, out);
}

// Round 16
// 84.798 us; speedup vs baseline: 2.6896x; 2.6896x over previous
//
#include <hip/hip_runtime.h>

// Partial-CRF NLL: chunked scan, TWO CONSUMER WAVES per block (TLP, not ILP).
// 256 blocks x 256 threads = 1 block/CU; block = (grp = bid&63, pair = bid>>6).
// wave0 = consumer chunk pair, wave1 = consumer chunk pair+4 (8 chunks x 64
// steps), waves 2-3 = producers (4 batches x 2 chains each). Each consumer
// is R14's verbatim per-step machinery (absmax 0.0): sigma-permuted register
// P, 28 bf16 MFMA (4-deep chains), tile-6 ds_bpermute — in its OWN register
// file on its OWN SIMD -> no spill (R15 lesson), no cross-block contention
// (R13 lesson). W=8 warmup (tau~0.07/step -> 6e-10; owning chunks' warmup
// windows are fully active); rescale at t%4==3; warmup ends on rescale;
// logZ reset after k=8 (unconditional: pair0-X steps k<9 are dummies);
// owner chunk (last active step in its 64-window) adds the STOP term.
// Ring: 8 slabs/chain, group-4 coupling, per-chain consumer flags.

typedef short s16x4 __attribute__((ext_vector_type(4)));
typedef short bf16x8 __attribute__((ext_vector_type(8)));
typedef float f32x4 __attribute__((ext_vector_type(4)));

constexpr int T = 512, L = 102;
constexpr int MS = 132;        // slab row stride (shorts)
constexpr int SLAB = 16 * MS;  // shorts per slab
constexpr int NSTEPS = 72;     // 8 warmup/dummy + 64 owned

__device__ __forceinline__ float bf2f(short s) {
  return __uint_as_float(((unsigned)(unsigned short)s) << 16);
}
__device__ __forceinline__ short f2bf(float x) {  // RNE, cold paths
  unsigned u = __float_as_uint(x);
  u += 0x7fffu + ((u >> 16) & 1u);
  return (short)(u >> 16);
}
__device__ __forceinline__ bf16x8 mk8(unsigned a, unsigned b, unsigned c,
                                      unsigned d) {
  union { unsigned u[4]; bf16x8 v; } x;
  x.u[0] = a; x.u[1] = b; x.u[2] = c; x.u[3] = d;
  return x.v;
}

#define ETILE(Tt, MM, RESv)                                                  \
  {                                                                          \
    float w0 = a[Tt][0] * bf2f(MM[0]);                                       \
    float w1 = a[Tt][1] * bf2f(MM[1]);                                       \
    float w2 = a[Tt][2] * bf2f(MM[2]);                                       \
    float w3 = a[Tt][3] * bf2f(MM[3]);                                       \
    if (RESv) { w0 *= cs; w1 *= cs; w2 *= cs; w3 *= cs; }                    \
    unsigned lo_, hi_;                                                       \
    asm("v_cvt_pk_bf16_f32 %0, %1, %2" : "=v"(lo_) : "v"(w0), "v"(w1));      \
    asm("v_cvt_pk_bf16_f32 %0, %1, %2" : "=v"(hi_) : "v"(w2), "v"(w3));      \
    pkA[Tt] = mmv ? lo_ : pkA[Tt];                                           \
    pkB[Tt] = mmv ? hi_ : pkB[Tt];                                           \
  }

// One scan step: direct in-step slab reads (4-deep MFMA chain covers LDS lat)
#define STEP(SB, MMVv, RESv)                                                 \
  {                                                                          \
    const bool mmv = (MMVv) != 0;                                            \
    const short* sln = mlb + (SB) + cc * MS;                                 \
    const s16x4 mm0 = *(const s16x4*)(sln + 0 + 8 * hi);                     \
    const s16x4 mm1 = *(const s16x4*)(sln + 4 + 8 * hi);                     \
    const s16x4 mm2 = *(const s16x4*)(sln + 32 + 8 * hi);                    \
    const s16x4 mm3 = *(const s16x4*)(sln + 36 + 8 * hi);                    \
    const s16x4 mm4 = *(const s16x4*)(sln + 64 + 8 * hi);                    \
    const s16x4 mm5 = *(const s16x4*)(sln + 68 + 8 * hi);                    \
    const s16x4 mm6 = *(const s16x4*)(sln + 96 + 4 * hi);                    \
    const unsigned q3d0 =                                                    \
        ((unsigned)__builtin_amdgcn_ds_bpermute(bpa, (int)pkA[6])) & himask; \
    const unsigned q3d1 =                                                    \
        ((unsigned)__builtin_amdgcn_ds_bpermute(bpa, (int)pkB[6])) & himask; \
    const unsigned q3d2 =                                                    \
        ((unsigned)__builtin_amdgcn_ds_bpermute(bpb, (int)pkA[6])) & himask; \
    const unsigned q3d3 =                                                    \
        ((unsigned)__builtin_amdgcn_ds_bpermute(bpb, (int)pkB[6])) & himask; \
    const bf16x8 q0 = mk8(pkA[0], pkB[0], pkA[1], pkB[1]);                   \
    const bf16x8 q1 = mk8(pkA[2], pkB[2], pkA[3], pkB[3]);                   \
    const bf16x8 q2 = mk8(pkA[4], pkB[4], pkA[5], pkB[5]);                   \
    const bf16x8 q3 = mk8(q3d0, q3d1, q3d2, q3d3);                           \
    f32x4 a[7];                                                              \
    _Pragma("unroll") for (int Tt = 0; Tt < 7; ++Tt)                         \
      a[Tt] = __builtin_amdgcn_mfma_f32_16x16x32_bf16(ef[Tt][0], q0, zf,     \
                                                      0, 0, 0);              \
    _Pragma("unroll") for (int Tt = 0; Tt < 7; ++Tt)                         \
      a[Tt] = __builtin_amdgcn_mfma_f32_16x16x32_bf16(ef[Tt][1], q1, a[Tt],  \
                                                      0, 0, 0);              \
    _Pragma("unroll") for (int Tt = 0; Tt < 7; ++Tt)                         \
      a[Tt] = __builtin_amdgcn_mfma_f32_16x16x32_bf16(ef[Tt][2], q2, a[Tt],  \
                                                      0, 0, 0);              \
    _Pragma("unroll") for (int Tt = 0; Tt < 7; ++Tt)                         \
      a[Tt] = __builtin_amdgcn_mfma_f32_16x16x32_bf16(ef[Tt][3], q3, a[Tt],  \
                                                      0, 0, 0);              \
    float cs = 1.f;                                                          \
    if (RESv) {                                                              \
      const float w1r = a[0][1] * bf2f(mm0[1]);                              \
      const float spre = mmv ? w1r : 1.0f;                                   \
      const float sh = __shfl(spre, cc);                                     \
      cs = __builtin_amdgcn_rcpf(sh);                                        \
      logZ += __logf(sh);                                                    \
    }                                                                        \
    ETILE(0, mm0, RESv) ETILE(1, mm1, RESv) ETILE(2, mm2, RESv)              \
    ETILE(3, mm3, RESv) ETILE(4, mm4, RESv) ETILE(5, mm5, RESv)              \
    ETILE(6, mm6, RESv)                                                      \
  }

__global__ __launch_bounds__(256, 1)
void crf_scan(const float* __restrict__ emit,
              const float* __restrict__ trans,
              const unsigned char* __restrict__ mask_b,
              const unsigned char* __restrict__ um_b,
              float* __restrict__ partials)
{
  const int tid = threadIdx.x, wid = tid >> 6, lane = tid & 63;
  const int bid = blockIdx.x;
  const int grp = bid & 63, pair = bid >> 6;      // pair in 0..3
  const int b8 = grp * 8;
  // bool layout: um[0,0,1] always True -> byte1==1 iff uint8, else LE int32
  const int ush = (um_b[1] != 0) ? 0 : 2;

  __shared__ __align__(16) short Ml[2][8][16][MS];
  __shared__ unsigned char Kmask[8][T];
  __shared__ int sflags[4];   // [0],[1]: producers; [2],[3]: consumers X,Y

  volatile int* pf0 = (volatile int*)&sflags[0];
  volatile int* pf1 = (volatile int*)&sflags[1];

  if (wid >= 2) {
    // ================= producer waves (wid 2,3; 4 batches x 2 chains) ====
    const int p    = wid - 2;
    const int boff = 4 * p;
    const int tagp = 2 * lane;
    const int tagc = (tagp <= 100) ? tagp : 100;
    const bool tv  = (tagp <= 100);
    const int tf0 = (pair << 6) - 8;
    const int tf1 = ((pair + 4) << 6) - 8;

    if (lane == 0) sflags[p] = 0;
    for (int i = lane; i < 4 * T; i += 64) {       // my 4 Kmask rows
      const int bb_ = i >> 9, tt = i & 511;
      Kmask[boff + bb_][tt] =
          mask_b[(((size_t)(b8 + boff + bb_)) * T + tt) << ush];
    }

    float2 e[4][2][4];
    int u0[4][2][4], u1[4][2][4];

    auto issueG = [&](int kk) {
#pragma unroll
      for (int s = 0; s < 4; ++s) {
#pragma unroll
        for (int c2 = 0; c2 < 2; ++c2) {
          int t = (c2 ? tf1 : tf0) + kk + s;
          t = (t < 1) ? 1 : ((t > 511) ? 511 : t);
#pragma unroll
          for (int i = 0; i < 4; ++i) {
            const size_t base = ((size_t)(b8 + boff + i) * T + t) * (size_t)L;
            e[s][c2][i] = *(const float2*)(emit + base + tagc);
            if (ush == 0) {
              const unsigned us =
                  *(const unsigned short*)(um_b + base + tagc);
              u0[s][c2][i] = us & 255u; u1[s][c2][i] = us >> 8;
            } else {
              const uint2 uv = *(const uint2*)(um_b + ((base + tagc) << 2));
              u0[s][c2][i] = (int)uv.x; u1[s][c2][i] = (int)uv.y;
            }
          }
        }
      }
    };
    auto stageG = [&](int kk) {
#pragma unroll
      for (int s = 0; s < 4; ++s) {
#pragma unroll
        for (int c2 = 0; c2 < 2; ++c2) {
          short* slab = &Ml[c2][(kk + s) & 7][0][0];
#pragma unroll
          for (int i = 0; i < 4; ++i) {
            const float e0 = tv ? __expf(e[s][c2][i].x) : 0.f;
            const float e1_ = tv ? __expf(e[s][c2][i].y) : 0.f;
            const float g0 = u0[s][c2][i] ? e0 : 0.f;
            const float g1 = u1[s][c2][i] ? e1_ : 0.f;
            unsigned pe, pg;
            asm("v_cvt_pk_bf16_f32 %0, %1, %2" : "=v"(pe) : "v"(e0), "v"(e1_));
            asm("v_cvt_pk_bf16_f32 %0, %1, %2" : "=v"(pg) : "v"(g0), "v"(g1));
            *(unsigned*)(slab + (2 * (boff + i))     * MS + tagp) = pe;
            *(unsigned*)(slab + (2 * (boff + i) + 1) * MS + tagp) = pg;
          }
        }
      }
    };

    volatile int* myf = (p == 0) ? pf0 : pf1;
    volatile int* cfX = (volatile int*)&sflags[2];
    volatile int* cfY = (volatile int*)&sflags[3];
    __syncthreads();
    issueG(0);
    int csnX = 0, csnY = 0;

    for (int kk = 0; kk < NSTEPS; kk += 4) {
      if (kk >= 8) {
        const int need = kk - 4;
        if (csnX < need || csnY < need) {
          int vx, vy;
          do { vx = *cfX; vy = *cfY; } while (vx < need || vy < need);
          csnX = vx; csnY = vy;
        }
      }
      stageG(kk);
      asm volatile("s_waitcnt lgkmcnt(0)" ::: "memory");
      if (lane == 0) *myf = kk + 4;
      issueG(kk + 4);
    }
  } else {
    // ========================= consumer waves (wid 0,1) ==================
    const int c2 = wid;
    if (lane == 0) sflags[2 + c2] = 0;
    __builtin_amdgcn_s_setprio(1);
    const int cc = lane & 15, hi = lane >> 4;
    const int myb = cc >> 1, batch = b8 + myb, goldc = cc & 1;
    const int t0c = (pair + 4 * c2) << 6;
    const int tfc = t0c - 8;
    const bool exact0 = (pair == 0) && (c2 == 0);
    const int sbase = c2 * 8 * SLAB;

    // A-frags (R6-verified): row rho=cc of tile Tt -> tag g(Tt,cc)
    bf16x8 ef[7][4];
#pragma unroll
    for (int Tt = 0; Tt < 7; ++Tt) {
      const int g = (Tt < 6)
          ? (32 * (Tt >> 1) + 4 * (Tt & 1) + 8 * (cc >> 2) + (cc & 3))
          : (96 + cc);
#pragma unroll
      for (int kk = 0; kk < 4; ++kk) {
        bf16x8 v;
#pragma unroll
        for (int j = 0; j < 8; ++j) {
          const int k = 32 * kk + 8 * hi + j;
          float e = 0.f;
          if (k < L && g < L) e = __expf(trans[k * L + g]);
          v[j] = f2bf(e);
        }
        ef[Tt][kk] = v;
      }
    }

    // init pk: exact t=0 (pair0 chain X) or uniform
    unsigned pkA[7], pkB[7];
    const size_t e0b = (size_t)batch * T * L;
    if (exact0) {
#pragma unroll
      for (int Tt = 0; Tt < 7; ++Tt) {
        const int s0 = (Tt < 6) ? (32 * (Tt >> 1) + 4 * (Tt & 1) + 8 * hi)
                                : (96 + 4 * hi);
        float w[4];
#pragma unroll
        for (int r = 0; r < 4; ++r) {
          const int tg = s0 + r;
          float x = 0.f;
          if (tg < L) {
            x = __expf(emit[e0b + tg] + trans[100 * L + tg]);
            if (goldc && !um_b[((size_t)(e0b + tg)) << ush]) x = 0.f;
          }
          w[r] = x;
        }
        asm("v_cvt_pk_bf16_f32 %0, %1, %2" : "=v"(pkA[Tt]) : "v"(w[0]), "v"(w[1]));
        asm("v_cvt_pk_bf16_f32 %0, %1, %2" : "=v"(pkB[Tt]) : "v"(w[2]), "v"(w[3]));
      }
    } else {
      const unsigned one2 = 0x3F803F80u;   // bf16 {1.0, 1.0}
#pragma unroll
      for (int Tt = 0; Tt < 6; ++Tt) { pkA[Tt] = one2; pkB[Tt] = one2; }
      pkA[6] = (hi == 0) ? one2 : ((hi == 1) ? one2 : 0u);
      pkB[6] = (hi == 0) ? one2 : 0u;
    }

    const int bpa = (cc + 16 * ((2 * hi) & 3)) << 2;       // tile-6 bpermute
    const int bpb = (cc + 16 * ((2 * hi + 1) & 3)) << 2;
    const unsigned himask = (hi < 2) ? 0xffffffffu : 0u;
    const short* mlb = &Ml[0][0][0][0];
    const unsigned* kmr = (const unsigned*)&Kmask[myb][0];
    const f32x4 zf = {0.f, 0.f, 0.f, 0.f};
    volatile int* cfv = (volatile int*)&sflags[2 + c2];
    float logZ = 0.f;
    int seen = 0;

    __syncthreads();

    for (int j = 0; j < 18; ++j) {
      const int k0 = 4 * j;
      if (seen < k0 + 4) {
        int v0, v1;
        do { v0 = *pf0; v1 = *pf1; } while (v0 < k0 + 4 || v1 < k0 + 4);
        seen = (v0 < v1) ? v0 : v1;
      }
      int x0 = sbase + ((k0 + 0) & 7) * SLAB;
      int x1 = sbase + ((k0 + 1) & 7) * SLAB;
      int x2 = sbase + ((k0 + 2) & 7) * SLAB;
      int x3 = sbase + ((k0 + 3) & 7) * SLAB;
      asm volatile("" : "+v"(x0), "+v"(x1), "+v"(x2), "+v"(x3) : "v"(seen));
      const int tb = tfc + k0;                       // tb % 4 == 0
      unsigned w = (tb >= 0) ? kmr[tb >> 2] : 0u;
      if (exact0 && tb == 0) w &= ~255u;             // t=0 is init, not a step
      const unsigned m0 = w & 255u, m1 = (w >> 8) & 255u;
      const unsigned m2 = (w >> 16) & 255u, m3 = w >> 24;
      STEP(x0, m0, false)
      STEP(x1, m1, false)
      STEP(x2, m2, false)
      STEP(x3, m3, true)                             // k%4==3 (t%4==3)
      asm volatile("s_waitcnt lgkmcnt(0)" ::: "memory");
      if (lane == 0) *cfv = k0 + 4;
      if (j == 1) logZ = 0.f;                        // end-of-warmup anchor
    }

    // final: tot over sigma map; owner adds STOP term
    float tot = 0.f;
#pragma unroll
    for (int Tt = 0; Tt < 7; ++Tt) {
      const int s0 = (Tt < 6) ? (32 * (Tt >> 1) + 4 * (Tt & 1) + 8 * hi)
                              : (96 + 4 * hi);
#pragma unroll
      for (int r = 0; r < 4; ++r) {
        const int tg = s0 + r;
        if (tg < L) {
          const unsigned pv = (r < 2) ? pkA[Tt] : pkB[Tt];
          const short bb = (short)((r & 1) ? (pv >> 16) : (pv & 0xffffu));
          tot += bf2f(bb) * __expf(trans[tg * L + 101]);
        }
      }
    }
    tot += __shfl_xor(tot, 16);
    tot += __shfl_xor(tot, 32);
    const int ae = (t0c + 64 >= T) ? 0 : (int)Kmask[myb][t0c + 64];
    const int own = (int)Kmask[myb][t0c] & (1 - ae);
    const float score = logZ + (own ? __logf(tot) : 0.f);
    float sgn = goldc ? -score : score;
    sgn += __shfl_xor(sgn, 1);
    sgn += __shfl_xor(sgn, 2);
    sgn += __shfl_xor(sgn, 4);
    sgn += __shfl_xor(sgn, 8);
    if (lane == 0) partials[2 * bid + c2] = sgn;
  }
}

__global__ void reduce_partials(const float* __restrict__ part,
                                float* __restrict__ out) {
  const int tid = threadIdx.x;
  float v = part[tid];
#pragma unroll
  for (int s = 1; s < 64; s <<= 1) v += __shfl_xor(v, s);
  __shared__ float ws[8];
  if ((tid & 63) == 0) ws[tid >> 6] = v;
  __syncthreads();
  if (tid == 0) {
    float t = 0.f;
#pragma unroll
    for (int w = 0; w < 8; ++w) t += ws[w];
    out[0] = t;
  }
}

extern "C" void kernel_launch(void* const* d_in, const int* in_sizes, int n_in,
                              void* d_out, int out_size, void* d_ws,
                              size_t ws_size, hipStream_t stream) {
  const float* emit = (const float*)d_in[0];
  const float* trn  = (const float*)d_in[1];
  const unsigned char* msk = (const unsigned char*)d_in[2];
  const unsigned char* umk = (const unsigned char*)d_in[3];
  float* out = (float*)d_out;
  float* pw  = (float*)d_ws;   // 512 partials (2 per block)

  crf_scan<<<dim3(256), dim3(256), 0, stream>>>(emit, trn, msk, umk, pw);
  reduce_partials<<<dim3(1), dim3(512), 0, stream>>>(pw, out);
}

// Round 17
// 78.040 us; speedup vs baseline: 2.9225x; 1.0866x over previous
//
#include <hip/hip_runtime.h>

// Partial-CRF NLL: chunked scan, FOUR consumer waves + FOUR private producers.
// 256 blocks x 512 threads = 1 block/CU, 8 waves (2/SIMD: consumer+producer).
// block = (grp = bid&63, quad = bid>>6). Consumer c2 (wid 0-3) runs chunk
// ck = quad + 4*c2 (16 chunks x 32 steps). Producer p (wid 4-7) stages ONLY
// chain p (8 batches, 4-step groups) -> private flag; zero cross-chain
// coupling (R16's min-over-flags convoy removed).
// Per-step machinery = R14/R16 verbatim (absmax 0.0): sigma-permuted register
// P, 28 bf16 MFMA (4-deep chains), tile-6 ds_bpermute. W=8 warmup
// (tau~0.07/active-step; owner chunks' warmup windows are provably fully
// active); rescale at t%4==3 (t0-1 = 32ck-1 == 3 mod 4: anchor holds);
// logZ reset after k=8; owner chunk (last active step in its 32-window)
// adds the STOP term. Ring: 8 slabs/chain (135KB LDS), group-4 coupling.

typedef short s16x4 __attribute__((ext_vector_type(4)));
typedef short bf16x8 __attribute__((ext_vector_type(8)));
typedef float f32x4 __attribute__((ext_vector_type(4)));

constexpr int T = 512, L = 102;
constexpr int MS = 132;        // slab row stride (shorts)
constexpr int SLAB = 16 * MS;  // shorts per slab
constexpr int NSTEPS = 40;     // 8 warmup/dummy + 32 owned

__device__ __forceinline__ float bf2f(short s) {
  return __uint_as_float(((unsigned)(unsigned short)s) << 16);
}
__device__ __forceinline__ short f2bf(float x) {  // RNE, cold paths
  unsigned u = __float_as_uint(x);
  u += 0x7fffu + ((u >> 16) & 1u);
  return (short)(u >> 16);
}
__device__ __forceinline__ bf16x8 mk8(unsigned a, unsigned b, unsigned c,
                                      unsigned d) {
  union { unsigned u[4]; bf16x8 v; } x;
  x.u[0] = a; x.u[1] = b; x.u[2] = c; x.u[3] = d;
  return x.v;
}

#define ETILE(Tt, MM, RESv)                                                  \
  {                                                                          \
    float w0 = a[Tt][0] * bf2f(MM[0]);                                       \
    float w1 = a[Tt][1] * bf2f(MM[1]);                                       \
    float w2 = a[Tt][2] * bf2f(MM[2]);                                       \
    float w3 = a[Tt][3] * bf2f(MM[3]);                                       \
    if (RESv) { w0 *= cs; w1 *= cs; w2 *= cs; w3 *= cs; }                    \
    unsigned lo_, hi_;                                                       \
    asm("v_cvt_pk_bf16_f32 %0, %1, %2" : "=v"(lo_) : "v"(w0), "v"(w1));      \
    asm("v_cvt_pk_bf16_f32 %0, %1, %2" : "=v"(hi_) : "v"(w2), "v"(w3));      \
    pkA[Tt] = mmv ? lo_ : pkA[Tt];                                           \
    pkB[Tt] = mmv ? hi_ : pkB[Tt];                                           \
  }

#define STEP(SB, MMVv, RESv)                                                 \
  {                                                                          \
    const bool mmv = (MMVv) != 0;                                            \
    const short* sln = mlb + (SB) + cc * MS;                                 \
    const s16x4 mm0 = *(const s16x4*)(sln + 0 + 8 * hi);                     \
    const s16x4 mm1 = *(const s16x4*)(sln + 4 + 8 * hi);                     \
    const s16x4 mm2 = *(const s16x4*)(sln + 32 + 8 * hi);                    \
    const s16x4 mm3 = *(const s16x4*)(sln + 36 + 8 * hi);                    \
    const s16x4 mm4 = *(const s16x4*)(sln + 64 + 8 * hi);                    \
    const s16x4 mm5 = *(const s16x4*)(sln + 68 + 8 * hi);                    \
    const s16x4 mm6 = *(const s16x4*)(sln + 96 + 4 * hi);                    \
    const unsigned q3d0 =                                                    \
        ((unsigned)__builtin_amdgcn_ds_bpermute(bpa, (int)pkA[6])) & himask; \
    const unsigned q3d1 =                                                    \
        ((unsigned)__builtin_amdgcn_ds_bpermute(bpa, (int)pkB[6])) & himask; \
    const unsigned q3d2 =                                                    \
        ((unsigned)__builtin_amdgcn_ds_bpermute(bpb, (int)pkA[6])) & himask; \
    const unsigned q3d3 =                                                    \
        ((unsigned)__builtin_amdgcn_ds_bpermute(bpb, (int)pkB[6])) & himask; \
    const bf16x8 q0 = mk8(pkA[0], pkB[0], pkA[1], pkB[1]);                   \
    const bf16x8 q1 = mk8(pkA[2], pkB[2], pkA[3], pkB[3]);                   \
    const bf16x8 q2 = mk8(pkA[4], pkB[4], pkA[5], pkB[5]);                   \
    const bf16x8 q3 = mk8(q3d0, q3d1, q3d2, q3d3);                           \
    f32x4 a[7];                                                              \
    _Pragma("unroll") for (int Tt = 0; Tt < 7; ++Tt)                         \
      a[Tt] = __builtin_amdgcn_mfma_f32_16x16x32_bf16(ef[Tt][0], q0, zf,     \
                                                      0, 0, 0);              \
    _Pragma("unroll") for (int Tt = 0; Tt < 7; ++Tt)                         \
      a[Tt] = __builtin_amdgcn_mfma_f32_16x16x32_bf16(ef[Tt][1], q1, a[Tt],  \
                                                      0, 0, 0);              \
    _Pragma("unroll") for (int Tt = 0; Tt < 7; ++Tt)                         \
      a[Tt] = __builtin_amdgcn_mfma_f32_16x16x32_bf16(ef[Tt][2], q2, a[Tt],  \
                                                      0, 0, 0);              \
    _Pragma("unroll") for (int Tt = 0; Tt < 7; ++Tt)                         \
      a[Tt] = __builtin_amdgcn_mfma_f32_16x16x32_bf16(ef[Tt][3], q3, a[Tt],  \
                                                      0, 0, 0);              \
    float cs = 1.f;                                                          \
    if (RESv) {                                                              \
      const float w1r = a[0][1] * bf2f(mm0[1]);                              \
      const float spre = mmv ? w1r : 1.0f;                                   \
      const float sh = __shfl(spre, cc);                                     \
      cs = __builtin_amdgcn_rcpf(sh);                                        \
      logZ += __logf(sh);                                                    \
    }                                                                        \
    ETILE(0, mm0, RESv) ETILE(1, mm1, RESv) ETILE(2, mm2, RESv)              \
    ETILE(3, mm3, RESv) ETILE(4, mm4, RESv) ETILE(5, mm5, RESv)              \
    ETILE(6, mm6, RESv)                                                      \
  }

__global__ __launch_bounds__(512, 1)
void crf_scan(const float* __restrict__ emit,
              const float* __restrict__ trans,
              const unsigned char* __restrict__ mask_b,
              const unsigned char* __restrict__ um_b,
              float* __restrict__ partials)
{
  const int tid = threadIdx.x, wid = tid >> 6, lane = tid & 63;
  const int bid = blockIdx.x;
  const int grp = bid & 63, quad = bid >> 6;      // quad in 0..3
  const int b8 = grp * 8;
  // bool layout: um[0,0,1] always True -> byte1==1 iff uint8, else LE int32
  const int ush = (um_b[1] != 0) ? 0 : 2;

  __shared__ __align__(16) short Ml[4][8][16][MS];
  __shared__ unsigned char Kmask[8][T];
  __shared__ int sflags[8];   // [0..3]: producers; [4..7]: consumers

  if (wid >= 4) {
    // ========= producer waves (wid 4..7): chain p, all 8 batches =========
    const int p    = wid - 4;
    const int tagp = 2 * lane;
    const int tagc = (tagp <= 100) ? tagp : 100;
    const bool tv  = (tagp <= 100);
    const int tfc  = ((quad + 4 * p) << 5) - 8;    // chunk start - warmup

    if (lane == 0) sflags[p] = 0;
    for (int i = lane; i < 2 * T; i += 64) {       // my 2 Kmask rows
      const int bb_ = i >> 9, tt = i & 511;
      Kmask[2 * p + bb_][tt] =
          mask_b[(((size_t)(b8 + 2 * p + bb_)) * T + tt) << ush];
    }

    float2 e[4][8];
    int u0[4][8], u1[4][8];

    auto issueG = [&](int kk) {
#pragma unroll
      for (int s = 0; s < 4; ++s) {
        int t = tfc + kk + s;
        t = (t < 1) ? 1 : ((t > 511) ? 511 : t);
#pragma unroll
        for (int i = 0; i < 8; ++i) {
          const size_t base = ((size_t)(b8 + i) * T + t) * (size_t)L;
          e[s][i] = *(const float2*)(emit + base + tagc);
          if (ush == 0) {
            const unsigned us = *(const unsigned short*)(um_b + base + tagc);
            u0[s][i] = us & 255u; u1[s][i] = us >> 8;
          } else {
            const uint2 uv = *(const uint2*)(um_b + ((base + tagc) << 2));
            u0[s][i] = (int)uv.x; u1[s][i] = (int)uv.y;
          }
        }
      }
    };
    auto stageG = [&](int kk) {
#pragma unroll
      for (int s = 0; s < 4; ++s) {
        short* slab = &Ml[p][(kk + s) & 7][0][0];
#pragma unroll
        for (int i = 0; i < 8; ++i) {
          const float e0 = tv ? __expf(e[s][i].x) : 0.f;
          const float e1_ = tv ? __expf(e[s][i].y) : 0.f;
          const float g0 = u0[s][i] ? e0 : 0.f;
          const float g1 = u1[s][i] ? e1_ : 0.f;
          unsigned pe, pg;
          asm("v_cvt_pk_bf16_f32 %0, %1, %2" : "=v"(pe) : "v"(e0), "v"(e1_));
          asm("v_cvt_pk_bf16_f32 %0, %1, %2" : "=v"(pg) : "v"(g0), "v"(g1));
          *(unsigned*)(slab + (2 * i)     * MS + tagp) = pe;
          *(unsigned*)(slab + (2 * i + 1) * MS + tagp) = pg;
        }
      }
    };

    volatile int* myf = (volatile int*)&sflags[p];
    volatile int* cf  = (volatile int*)&sflags[4 + p];
    __syncthreads();
    issueG(0);
    int csn = 0;

    for (int kk = 0; kk < NSTEPS; kk += 4) {
      if (kk >= 8 && csn < kk - 4) {
        int v; do { v = *cf; } while (v < kk - 4);
        csn = v;
      }
      stageG(kk);
      asm volatile("s_waitcnt lgkmcnt(0)" ::: "memory");
      if (lane == 0) *myf = kk + 4;
      issueG(kk + 4);
    }
  } else {
    // ========================= consumer waves (wid 0..3) =================
    const int c2 = wid;
    if (lane == 0) sflags[4 + c2] = 0;
    __builtin_amdgcn_s_setprio(1);
    const int cc = lane & 15, hi = lane >> 4;
    const int myb = cc >> 1, batch = b8 + myb, goldc = cc & 1;
    const int ck  = quad + 4 * c2;                 // chunk 0..15
    const int t0c = ck << 5;
    const int tfc = t0c - 8;
    const bool exact0 = (ck == 0);
    const int sbase = c2 * 8 * SLAB;

    // A-frags (R6-verified): row rho=cc of tile Tt -> tag g(Tt,cc)
    bf16x8 ef[7][4];
#pragma unroll
    for (int Tt = 0; Tt < 7; ++Tt) {
      const int g = (Tt < 6)
          ? (32 * (Tt >> 1) + 4 * (Tt & 1) + 8 * (cc >> 2) + (cc & 3))
          : (96 + cc);
#pragma unroll
      for (int kk = 0; kk < 4; ++kk) {
        bf16x8 v;
#pragma unroll
        for (int j = 0; j < 8; ++j) {
          const int k = 32 * kk + 8 * hi + j;
          float e = 0.f;
          if (k < L && g < L) e = __expf(trans[k * L + g]);
          v[j] = f2bf(e);
        }
        ef[Tt][kk] = v;
      }
    }

    // init pk: exact t=0 (chunk 0) or uniform
    unsigned pkA[7], pkB[7];
    const size_t e0b = (size_t)batch * T * L;
    if (exact0) {
#pragma unroll
      for (int Tt = 0; Tt < 7; ++Tt) {
        const int s0 = (Tt < 6) ? (32 * (Tt >> 1) + 4 * (Tt & 1) + 8 * hi)
                                : (96 + 4 * hi);
        float w[4];
#pragma unroll
        for (int r = 0; r < 4; ++r) {
          const int tg = s0 + r;
          float x = 0.f;
          if (tg < L) {
            x = __expf(emit[e0b + tg] + trans[100 * L + tg]);
            if (goldc && !um_b[((size_t)(e0b + tg)) << ush]) x = 0.f;
          }
          w[r] = x;
        }
        asm("v_cvt_pk_bf16_f32 %0, %1, %2" : "=v"(pkA[Tt]) : "v"(w[0]), "v"(w[1]));
        asm("v_cvt_pk_bf16_f32 %0, %1, %2" : "=v"(pkB[Tt]) : "v"(w[2]), "v"(w[3]));
      }
    } else {
      const unsigned one2 = 0x3F803F80u;   // bf16 {1.0, 1.0}
#pragma unroll
      for (int Tt = 0; Tt < 6; ++Tt) { pkA[Tt] = one2; pkB[Tt] = one2; }
      pkA[6] = (hi == 0) ? one2 : ((hi == 1) ? one2 : 0u);
      pkB[6] = (hi == 0) ? one2 : 0u;
    }

    const int bpa = (cc + 16 * ((2 * hi) & 3)) << 2;       // tile-6 bpermute
    const int bpb = (cc + 16 * ((2 * hi + 1) & 3)) << 2;
    const unsigned himask = (hi < 2) ? 0xffffffffu : 0u;
    const short* mlb = &Ml[0][0][0][0];
    const unsigned* kmr = (const unsigned*)&Kmask[myb][0];
    const f32x4 zf = {0.f, 0.f, 0.f, 0.f};
    volatile int* pfm = (volatile int*)&sflags[c2];        // my producer
    volatile int* cfv = (volatile int*)&sflags[4 + c2];
    float logZ = 0.f;
    int seen = 0;

    __syncthreads();

    for (int j = 0; j < 10; ++j) {
      const int k0 = 4 * j;
      if (seen < k0 + 4) {
        int v; do { v = *pfm; } while (v < k0 + 4);
        seen = v;
      }
      int x0 = sbase + ((k0 + 0) & 7) * SLAB;
      int x1 = sbase + ((k0 + 1) & 7) * SLAB;
      int x2 = sbase + ((k0 + 2) & 7) * SLAB;
      int x3 = sbase + ((k0 + 3) & 7) * SLAB;
      asm volatile("" : "+v"(x0), "+v"(x1), "+v"(x2), "+v"(x3) : "v"(seen));
      const int tb = tfc + k0;                       // tb % 4 == 0
      unsigned w = (tb >= 0) ? kmr[tb >> 2] : 0u;
      if (exact0 && tb == 0) w &= ~255u;             // t=0 is init, not a step
      const unsigned m0 = w & 255u, m1 = (w >> 8) & 255u;
      const unsigned m2 = (w >> 16) & 255u, m3 = w >> 24;
      STEP(x0, m0, false)
      STEP(x1, m1, false)
      STEP(x2, m2, false)
      STEP(x3, m3, true)                             // t%4==3: rescale
      asm volatile("s_waitcnt lgkmcnt(0)" ::: "memory");
      if (lane == 0) *cfv = k0 + 4;
      if (j == 1) logZ = 0.f;                        // end-of-warmup anchor
    }

    // final: tot over sigma map; owner adds STOP term
    float tot = 0.f;
#pragma unroll
    for (int Tt = 0; Tt < 7; ++Tt) {
      const int s0 = (Tt < 6) ? (32 * (Tt >> 1) + 4 * (Tt & 1) + 8 * hi)
                              : (96 + 4 * hi);
#pragma unroll
      for (int r = 0; r < 4; ++r) {
        const int tg = s0 + r;
        if (tg < L) {
          const unsigned pv = (r < 2) ? pkA[Tt] : pkB[Tt];
          const short bb = (short)((r & 1) ? (pv >> 16) : (pv & 0xffffu));
          tot += bf2f(bb) * __expf(trans[tg * L + 101]);
        }
      }
    }
    tot += __shfl_xor(tot, 16);
    tot += __shfl_xor(tot, 32);
    const int ae = (t0c + 32 >= T) ? 0 : (int)Kmask[myb][t0c + 32];
    const int own = (int)Kmask[myb][t0c] & (1 - ae);
    const float score = logZ + (own ? __logf(tot) : 0.f);
    float sgn = goldc ? -score : score;
    sgn += __shfl_xor(sgn, 1);
    sgn += __shfl_xor(sgn, 2);
    sgn += __shfl_xor(sgn, 4);
    sgn += __shfl_xor(sgn, 8);
    if (lane == 0) partials[4 * bid + c2] = sgn;
  }
}

__global__ void reduce_partials(const float* __restrict__ part,
                                float* __restrict__ out) {
  const int tid = threadIdx.x;
  float v = part[tid];
#pragma unroll
  for (int s = 1; s < 64; s <<= 1) v += __shfl_xor(v, s);
  __shared__ float ws[16];
  if ((tid & 63) == 0) ws[tid >> 6] = v;
  __syncthreads();
  if (tid == 0) {
    float t = 0.f;
#pragma unroll
    for (int w = 0; w < 16; ++w) t += ws[w];
    out[0] = t;
  }
}

extern "C" void kernel_launch(void* const* d_in, const int* in_sizes, int n_in,
                              void* d_out, int out_size, void* d_ws,
                              size_t ws_size, hipStream_t stream) {
  const float* emit = (const float*)d_in[0];
  const float* trn  = (const float*)d_in[1];
  const unsigned char* msk = (const unsigned char*)d_in[2];
  const unsigned char* umk = (const unsigned char*)d_in[3];
  float* out = (float*)d_out;
  float* pw  = (float*)d_ws;   // 1024 partials (4 per block)

  crf_scan<<<dim3(256), dim3(512), 0, stream>>>(emit, trn, msk, umk, pw);
  reduce_partials<<<dim3(1), dim3(1024), 0, stream>>>(pw, out);
}